// Round 3
// baseline (1099.551 us; speedup 1.0000x reference)
//
#include <hip/hip_runtime.h>

// Lovasz-Softmax loss, histogram formulation (sort-free).
// logits: [8,19,384,384] fp32; labels passed by harness as int32 (NOT int64 —
// harness casts integer inputs to const int*; reading as long long faulted).
// Per-class loss is tie-order invariant => quantize errors to nbins bins;
// loss error <= 1/(2*nbins) (jacc is monotone along the sorted order).

#define NCLS 19
#define HW   147456          // 384*384
#define NPIX 1179648         // 8*HW
#define MAXBINS 16384
#define MAXCOPIES 8
#define IGNORE_IDX (-100)

// hist layout per copy: [class][fg][bin], uint32. copy stride = NCLS*2*nbins.

__global__ __launch_bounds__(256) void lovasz_hist(
    const float* __restrict__ logits,
    const int* __restrict__ labels,
    unsigned int* __restrict__ hist,
    int nbins, int copies)
{
    int p = blockIdx.x * 256 + threadIdx.x;
    if (p >= NPIX) return;
    int n  = p / HW;
    int hw = p - n * HW;
    const float* base = logits + (size_t)n * (NCLS * HW) + hw;

    float x[NCLS];
    float mx = -1e30f;
#pragma unroll
    for (int c = 0; c < NCLS; ++c) {
        x[c] = base[(size_t)c * HW];
        mx = fmaxf(mx, x[c]);
    }
    float denom = 0.f;
#pragma unroll
    for (int c = 0; c < NCLS; ++c) {
        x[c] = __expf(x[c] - mx);
        denom += x[c];
    }
    float rd = 1.f / denom;

    int lab = labels[p];
    if (lab == IGNORE_IDX) return;   // ignored pixels contribute exactly 0

    unsigned int* h = hist + (size_t)(blockIdx.x % copies) * (NCLS * 2 * nbins);
    float fb = (float)nbins;
#pragma unroll
    for (int c = 0; c < NCLS; ++c) {
        float prob = x[c] * rd;
        int   fg   = (c == lab) ? 1 : 0;
        float err  = fg ? (1.f - prob) : prob;
        int bin = (int)(err * fb);
        bin = bin < 0 ? 0 : (bin > nbins - 1 ? nbins - 1 : bin);
        atomicAdd(&h[(size_t)(c * 2 + fg) * nbins + bin], 1u);
    }
}

// One block per class. Bins scanned from high err to low; per-bin contribution
// telescopes: e_b * (jacc(after) - jacc(before)).
__global__ __launch_bounds__(256) void lovasz_reduce(
    const unsigned int* __restrict__ hist,
    float* __restrict__ out,
    int nbins, int copies)
{
    const int c = blockIdx.x;
    const int t = threadIdx.x;
    const int lpt = (nbins + 255) / 256;   // bins per thread (descending order)
    const int j0 = t * lpt;
    const int j1 = (j0 + lpt < nbins) ? (j0 + lpt) : nbins;

    __shared__ unsigned int s_cnt[256], s_m[256];
    __shared__ double s_loss[256];

    const size_t copy_stride = (size_t)NCLS * 2 * nbins;
    const unsigned int* h0 = hist + (size_t)(c * 2 + 0) * nbins;
    const unsigned int* h1 = hist + (size_t)(c * 2 + 1) * nbins;

    // pass 1: per-thread totals over its (descending-err) bin range
    unsigned int csum = 0, msum = 0;
    for (int j = j0; j < j1; ++j) {
        int bin = nbins - 1 - j;
        unsigned int a = 0, b = 0;
        for (int k = 0; k < copies; ++k) {
            a += h0[(size_t)k * copy_stride + bin];
            b += h1[(size_t)k * copy_stride + bin];
        }
        csum += a + b;
        msum += b;
    }
    s_cnt[t] = csum; s_m[t] = msum;
    __syncthreads();

    // exclusive scan over threads (descending-err order) + total fg count
    unsigned long long nb = 0, mb = 0, gts = 0;
    for (int i = 0; i < 256; ++i) {
        unsigned int ci = s_cnt[i], mi = s_m[i];
        if (i < t) { nb += ci; mb += mi; }
        gts += mi;
    }
    double gtsd = (double)gts;

    // pass 2: per-bin telescoped contributions (fp64: jacc differences cancel)
    double loss = 0.0;
    unsigned long long nn = nb, mm = mb;
    for (int j = j0; j < j1; ++j) {
        int bin = nbins - 1 - j;
        unsigned int a = 0, b = 0;
        for (int k = 0; k < copies; ++k) {
            a += h0[(size_t)k * copy_stride + bin];
            b += h1[(size_t)k * copy_stride + bin];
        }
        unsigned int cc = a + b;
        if (cc) {
            double jb = (nn == 0) ? 0.0
                : 1.0 - (gtsd - (double)mm) / (gtsd + (double)nn - (double)mm);
            unsigned long long n2 = nn + cc, m2 = mm + b;
            double ja = 1.0 - (gtsd - (double)m2) / (gtsd + (double)n2 - (double)m2);
            loss += (((double)bin + 0.5) / (double)nbins) * (ja - jb);
            nn = n2; mm = m2;
        }
    }
    s_loss[t] = loss;
    __syncthreads();
    for (int s = 128; s > 0; s >>= 1) {
        if (t < s) s_loss[t] += s_loss[t + s];
        __syncthreads();
    }
    if (t == 0) atomicAdd(out, (float)(s_loss[0] / (double)NCLS));
}

extern "C" void kernel_launch(void* const* d_in, const int* in_sizes, int n_in,
                              void* d_out, int out_size, void* d_ws, size_t ws_size,
                              hipStream_t stream)
{
    const float* logits = (const float*)d_in[0];
    const int*   labels = (const int*)d_in[1];
    float* out = (float*)d_out;
    unsigned int* hist = (unsigned int*)d_ws;

    // adaptive sizing: per-copy bytes = NCLS*2*nbins*4 = 152*nbins
    int nbins = MAXBINS;
    while (nbins >= 32 && (size_t)NCLS * 2 * nbins * 4 > ws_size) nbins >>= 1;

    hipMemsetAsync(d_out, 0, sizeof(float) * (size_t)out_size, stream);

    if ((size_t)NCLS * 2 * nbins * 4 <= ws_size) {   // workspace usable
        size_t copy_bytes = (size_t)NCLS * 2 * nbins * 4;
        int copies = (int)(ws_size / copy_bytes);
        if (copies > MAXCOPIES) copies = MAXCOPIES;
        if (copies < 1) copies = 1;

        hipMemsetAsync(d_ws, 0, copy_bytes * (size_t)copies, stream);
        lovasz_hist<<<(NPIX + 255) / 256, 256, 0, stream>>>(logits, labels, hist,
                                                            nbins, copies);
        lovasz_reduce<<<NCLS, 256, 0, stream>>>(hist, out, nbins, copies);
    }
    // else: ws_size pathologically small — leave out=0 rather than fault
}

// Round 4
// 180.145 us; speedup vs baseline: 6.1037x; 6.1037x over previous
//
#include <hip/hip_runtime.h>

// Lovasz-Softmax loss — sort-free histogram formulation.
// logits [8,19,384,384] fp32, labels int32 (harness passes integers as int*),
// out: scalar fp32.
// Loss is tie-order invariant => quantize errors to NBINS bins; loss error
// <= 1/(2*NBINS) = 2e-3 << 1.9e-2 threshold.
// R3 post-mortem: 22.4M global atomics caused 623 MB of HBM write traffic
// (cross-XCD cacheline ping-pong), 775 us. Now: private LDS histograms +
// atomic-free hierarchical merge.

#define NCLS 19
#define HW   147456          // 384*384
#define NPIX 1179648         // 8*HW
#define NBINS 256            // compile-time: LDS hist = 19*2*256*4 = 38912 B
#define HTOT  (NCLS * 2 * NBINS)   // 9728 entries per hist copy
#define MAXNB 1024
#define MPARTS 8
#define IGNORE_IDX (-100)

// ws layout: [NB][HTOT] u32 private copies, then [MPARTS][HTOT] u32 merged.

__global__ __launch_bounds__(256) void lovasz_hist(
    const float* __restrict__ logits,
    const int* __restrict__ labels,
    unsigned int* __restrict__ hist,
    int nblocks)
{
    __shared__ unsigned int sh[HTOT];
    const int t = threadIdx.x;
    for (int i = t; i < HTOT; i += 256) sh[i] = 0;
    __syncthreads();

    for (int p = blockIdx.x * 256 + t; p < NPIX; p += nblocks * 256) {
        int lab = labels[p];
        if (lab == IGNORE_IDX) continue;   // ignored pixels contribute 0

        int n  = p / HW;
        int hw = p - n * HW;
        const float* base = logits + (size_t)n * (NCLS * HW) + hw;

        float x[NCLS];
        float mx = -1e30f;
#pragma unroll
        for (int c = 0; c < NCLS; ++c) {
            x[c] = base[(size_t)c * HW];
            mx = fmaxf(mx, x[c]);
        }
        float denom = 0.f;
#pragma unroll
        for (int c = 0; c < NCLS; ++c) {
            x[c] = __expf(x[c] - mx);
            denom += x[c];
        }
        float rd = 1.f / denom;

#pragma unroll
        for (int c = 0; c < NCLS; ++c) {
            float prob = x[c] * rd;
            int   fg   = (c == lab) ? 1 : 0;
            float err  = fg ? (1.f - prob) : prob;
            int bin = (int)(err * (float)NBINS);
            bin = bin < 0 ? 0 : (bin > NBINS - 1 ? NBINS - 1 : bin);
            atomicAdd(&sh[(c * 2 + fg) * NBINS + bin], 1u);
        }
    }
    __syncthreads();
    // flush private LDS hist to private global copy (plain coalesced stores)
    unsigned int* dst = hist + (size_t)blockIdx.x * HTOT;
    for (int i = t; i < HTOT; i += 256) dst[i] = sh[i];
}

// Tree-merge NB private copies into MPARTS copies. grid = (ceil(HTOT/256), MPARTS)
__global__ __launch_bounds__(256) void lovasz_merge(
    const unsigned int* __restrict__ hist,
    unsigned int* __restrict__ merged,
    int nb)
{
    int bin  = blockIdx.x * 256 + threadIdx.x;
    if (bin >= HTOT) return;
    int part = blockIdx.y;
    int lo = part * nb / MPARTS, hi = (part + 1) * nb / MPARTS;
    unsigned int s = 0;
    for (int k = lo; k < hi; ++k) s += hist[(size_t)k * HTOT + bin];
    merged[(size_t)part * HTOT + bin] = s;
}

// One block per class; 1 bin/thread; telescoped Lovasz over descending bins.
__global__ __launch_bounds__(256) void lovasz_reduce(
    const unsigned int* __restrict__ merged,
    float* __restrict__ out)
{
    const int c = blockIdx.x;
    const int t = threadIdx.x;

    __shared__ unsigned int s_cnt[256], s_m[256];
    __shared__ double s_loss[256];

    const unsigned int* h0 = merged + (size_t)(c * 2 + 0) * NBINS;
    const unsigned int* h1 = merged + (size_t)(c * 2 + 1) * NBINS;

    const int bin = NBINS - 1 - t;     // thread t owns the t-th highest-err bin
    unsigned int a = 0, b = 0;
    for (int k = 0; k < MPARTS; ++k) {
        a += h0[(size_t)k * HTOT + bin];
        b += h1[(size_t)k * HTOT + bin];
    }
    s_cnt[t] = a + b; s_m[t] = b;
    __syncthreads();

    // exclusive scan over threads (descending-err order) + total fg count
    unsigned long long nb = 0, mb = 0, gts = 0;
    for (int i = 0; i < 256; ++i) {
        unsigned int ci = s_cnt[i], mi = s_m[i];
        if (i < t) { nb += ci; mb += mi; }
        gts += mi;
    }
    double gtsd = (double)gts;

    // telescoped contribution of this bin (fp64: jacc differences cancel)
    double loss = 0.0;
    unsigned int cc = a + b;
    if (cc) {
        double jb = (nb == 0) ? 0.0
            : 1.0 - (gtsd - (double)mb) / (gtsd + (double)nb - (double)mb);
        unsigned long long n2 = nb + cc, m2 = mb + b;
        double ja = 1.0 - (gtsd - (double)m2) / (gtsd + (double)n2 - (double)m2);
        loss = (((double)bin + 0.5) / (double)NBINS) * (ja - jb);
    }
    s_loss[t] = loss;
    __syncthreads();
    for (int s = 128; s > 0; s >>= 1) {
        if (t < s) s_loss[t] += s_loss[t + s];
        __syncthreads();
    }
    if (t == 0) atomicAdd(out, (float)(s_loss[0] / (double)NCLS));
}

extern "C" void kernel_launch(void* const* d_in, const int* in_sizes, int n_in,
                              void* d_out, int out_size, void* d_ws, size_t ws_size,
                              hipStream_t stream)
{
    const float* logits = (const float*)d_in[0];
    const int*   labels = (const int*)d_in[1];
    float* out = (float*)d_out;
    unsigned int* hist = (unsigned int*)d_ws;

    hipMemsetAsync(d_out, 0, sizeof(float) * (size_t)out_size, stream);

    const size_t copy_bytes = (size_t)HTOT * 4;
    // need NB private copies + MPARTS merged copies in ws
    long long avail = (long long)(ws_size / copy_bytes) - MPARTS;
    int nb = (int)(avail > MAXNB ? MAXNB : avail);
    if (nb < 1) return;  // ws pathologically small — leave out=0 rather than fault

    unsigned int* merged = hist + (size_t)nb * HTOT;

    lovasz_hist<<<nb, 256, 0, stream>>>(logits, labels, hist, nb);
    dim3 mg((HTOT + 255) / 256, MPARTS);
    lovasz_merge<<<mg, 256, 0, stream>>>(hist, merged, nb);
    lovasz_reduce<<<NCLS, 256, 0, stream>>>(merged, out);
}

// Round 5
// 170.054 us; speedup vs baseline: 6.4659x; 1.0593x over previous
//
#include <hip/hip_runtime.h>

// Lovasz-Softmax loss — sort-free histogram formulation.
// logits [8,19,384,384] fp32, labels int32 (harness passes integers as int*),
// out: scalar fp32.
// Loss is tie-order invariant => quantize errors to NBINS bins; loss error
// <= 1/(2*NBINS) = 2e-3 << 1.9e-2 threshold (R4 absmax printed 0.0).
// R3->R4: global atomics -> private LDS hists (775us -> <53us hist).
// R5: 1024-thread blocks @ 32 waves/CU (was 16), nb 1024->512 (halves
// flush/merge traffic, amortizes LDS init 4x).

#define NCLS 19
#define HW   147456          // 384*384
#define NPIX 1179648         // 8*HW
#define NBINS 256            // LDS hist = 19*2*256*4 = 38912 B
#define HTOT  (NCLS * 2 * NBINS)   // 9728 entries per hist copy
#define NB    512            // hist grid: 2 blocks/CU on 256 CUs
#define TPB   1024
#define MPARTS 8
#define IGNORE_IDX (-100)

// ws layout: [NB][HTOT] u32 private copies, then [MPARTS][HTOT] u32 merged.

__global__ __launch_bounds__(TPB, 8) void lovasz_hist(
    const float* __restrict__ logits,
    const int* __restrict__ labels,
    unsigned int* __restrict__ hist)
{
    __shared__ unsigned int sh[HTOT];
    const int t = threadIdx.x;
    for (int i = t; i < HTOT; i += TPB) sh[i] = 0;
    __syncthreads();

    for (int p = blockIdx.x * TPB + t; p < NPIX; p += NB * TPB) {
        int lab = labels[p];
        if (lab == IGNORE_IDX) continue;   // ignored pixels contribute 0

        int n  = p / HW;
        int hw = p - n * HW;
        const float* base = logits + (size_t)n * (NCLS * HW) + hw;

        float x[NCLS];
        float mx = -1e30f;
#pragma unroll
        for (int c = 0; c < NCLS; ++c) {
            x[c] = base[(size_t)c * HW];
            mx = fmaxf(mx, x[c]);
        }
        float denom = 0.f;
#pragma unroll
        for (int c = 0; c < NCLS; ++c) {
            x[c] = __expf(x[c] - mx);
            denom += x[c];
        }
        float rd = 1.f / denom;

#pragma unroll
        for (int c = 0; c < NCLS; ++c) {
            float prob = x[c] * rd;
            int   fg   = (c == lab) ? 1 : 0;
            float err  = fg ? (1.f - prob) : prob;
            int bin = (int)(err * (float)NBINS);
            bin = bin < 0 ? 0 : (bin > NBINS - 1 ? NBINS - 1 : bin);
            atomicAdd(&sh[(c * 2 + fg) * NBINS + bin], 1u);
        }
    }
    __syncthreads();
    // flush private LDS hist to private global copy (plain coalesced stores)
    unsigned int* dst = hist + (size_t)blockIdx.x * HTOT;
    for (int i = t; i < HTOT; i += TPB) dst[i] = sh[i];
}

// Tree-merge NB private copies into MPARTS copies. grid = (ceil(HTOT/256), MPARTS)
__global__ __launch_bounds__(256) void lovasz_merge(
    const unsigned int* __restrict__ hist,
    unsigned int* __restrict__ merged)
{
    int bin  = blockIdx.x * 256 + threadIdx.x;
    if (bin >= HTOT) return;
    int part = blockIdx.y;
    int lo = part * NB / MPARTS, hi = (part + 1) * NB / MPARTS;
    unsigned int s = 0;
    for (int k = lo; k < hi; ++k) s += hist[(size_t)k * HTOT + bin];
    merged[(size_t)part * HTOT + bin] = s;
}

// One block per class; 1 bin/thread; telescoped Lovasz over descending bins.
__global__ __launch_bounds__(256) void lovasz_reduce(
    const unsigned int* __restrict__ merged,
    float* __restrict__ out)
{
    const int c = blockIdx.x;
    const int t = threadIdx.x;

    __shared__ unsigned int s_cnt[256], s_m[256];
    __shared__ double s_loss[256];

    const unsigned int* h0 = merged + (size_t)(c * 2 + 0) * NBINS;
    const unsigned int* h1 = merged + (size_t)(c * 2 + 1) * NBINS;

    const int bin = NBINS - 1 - t;     // thread t owns the t-th highest-err bin
    unsigned int a = 0, b = 0;
    for (int k = 0; k < MPARTS; ++k) {
        a += h0[(size_t)k * HTOT + bin];
        b += h1[(size_t)k * HTOT + bin];
    }
    s_cnt[t] = a + b; s_m[t] = b;
    __syncthreads();

    // exclusive scan over threads (descending-err order) + total fg count
    unsigned long long nb = 0, mb = 0, gts = 0;
    for (int i = 0; i < 256; ++i) {
        unsigned int ci = s_cnt[i], mi = s_m[i];
        if (i < t) { nb += ci; mb += mi; }
        gts += mi;
    }
    double gtsd = (double)gts;

    // telescoped contribution of this bin (fp64: jacc differences cancel)
    double loss = 0.0;
    unsigned int cc = a + b;
    if (cc) {
        double jb = (nb == 0) ? 0.0
            : 1.0 - (gtsd - (double)mb) / (gtsd + (double)nb - (double)mb);
        unsigned long long n2 = nb + cc, m2 = mb + b;
        double ja = 1.0 - (gtsd - (double)m2) / (gtsd + (double)n2 - (double)m2);
        loss = (((double)bin + 0.5) / (double)NBINS) * (ja - jb);
    }
    s_loss[t] = loss;
    __syncthreads();
    for (int s = 128; s > 0; s >>= 1) {
        if (t < s) s_loss[t] += s_loss[t + s];
        __syncthreads();
    }
    if (t == 0) atomicAdd(out, (float)(s_loss[0] / (double)NCLS));
}

extern "C" void kernel_launch(void* const* d_in, const int* in_sizes, int n_in,
                              void* d_out, int out_size, void* d_ws, size_t ws_size,
                              hipStream_t stream)
{
    const float* logits = (const float*)d_in[0];
    const int*   labels = (const int*)d_in[1];
    float* out = (float*)d_out;
    unsigned int* hist = (unsigned int*)d_ws;

    hipMemsetAsync(d_out, 0, sizeof(float) * (size_t)out_size, stream);

    const size_t need = (size_t)(NB + MPARTS) * HTOT * 4;  // ~20.2 MB
    if (ws_size < need) return;  // ws too small — leave out=0 rather than fault

    unsigned int* merged = hist + (size_t)NB * HTOT;

    lovasz_hist<<<NB, TPB, 0, stream>>>(logits, labels, hist);
    dim3 mg((HTOT + 255) / 256, MPARTS);
    lovasz_merge<<<mg, 256, 0, stream>>>(hist, merged);
    lovasz_reduce<<<NCLS, 256, 0, stream>>>(merged, out);
}

// Round 6
// 161.719 us; speedup vs baseline: 6.7991x; 1.0515x over previous
//
#include <hip/hip_runtime.h>

// Lovasz-Softmax loss — sort-free histogram formulation.
// logits [8,19,384,384] fp32, labels int32 (harness passes integers as int*),
// out: scalar fp32.
// Loss is tie-order invariant => quantize errors to NBINS bins; midpoint
// quantization error <= 1/(2*NBINS) = 3.9e-3 << 1.9e-2 threshold (absmax was
// 0.000 at 256 bins; errors average out).
// R3->R4: global atomics -> private LDS hists (775us -> <53us hist).
// R5->R6: softmax probs cluster near 1/19 => wave lanes hammer the same few
// bins => same-address LDS-atomic serialization. Fix: 4 sub-histograms per
// block selected by quarter-wave, interleaved in low 2 addr bits (different
// banks per lane-group). Max serialization 64-way -> 16-way.

#define NCLS 19
#define HW   147456          // 384*384
#define NPIX 1179648         // 8*HW
#define NBINS 128
#define HTOT  (NCLS * 2 * NBINS)   // 4864 entries per merged copy
#define NSUB  4
#define NB    512            // hist grid: 2 blocks/CU on 256 CUs
#define TPB   1024
#define MPARTS 8
#define IGNORE_IDX (-100)

// ws layout: [NB][HTOT] u32 private copies, then [MPARTS][HTOT] u32 merged.

__global__ __launch_bounds__(TPB, 8) void lovasz_hist(
    const float* __restrict__ logits,
    const int* __restrict__ labels,
    unsigned int* __restrict__ hist)
{
    __shared__ unsigned int sh[HTOT * NSUB];   // 77824 B: 2 blocks/CU
    const int t = threadIdx.x;
    for (int i = t; i < HTOT * NSUB; i += TPB) sh[i] = 0;
    __syncthreads();

    const int sub = (t >> 4) & (NSUB - 1);     // quarter-wave -> sub-histogram

    for (int p = blockIdx.x * TPB + t; p < NPIX; p += NB * TPB) {
        int lab = labels[p];
        if (lab == IGNORE_IDX) continue;   // ignored pixels contribute 0

        int n  = p / HW;
        int hw = p - n * HW;
        const float* base = logits + (size_t)n * (NCLS * HW) + hw;

        float x[NCLS];
        float mx = -1e30f;
#pragma unroll
        for (int c = 0; c < NCLS; ++c) {
            x[c] = base[(size_t)c * HW];
            mx = fmaxf(mx, x[c]);
        }
        float denom = 0.f;
#pragma unroll
        for (int c = 0; c < NCLS; ++c) {
            x[c] = __expf(x[c] - mx);
            denom += x[c];
        }
        float rd = 1.f / denom;

#pragma unroll
        for (int c = 0; c < NCLS; ++c) {
            float prob = x[c] * rd;
            int   fg   = (c == lab) ? 1 : 0;
            float err  = fg ? (1.f - prob) : prob;
            int bin = (int)(err * (float)NBINS);
            bin = bin < 0 ? 0 : (bin > NBINS - 1 ? NBINS - 1 : bin);
            // sub-copy interleaved in low bits: lane-groups hit distinct banks
            atomicAdd(&sh[(((c * 2 + fg) * NBINS + bin) << 2) + sub], 1u);
        }
    }
    __syncthreads();
    // sum 4 sub-copies, flush one copy with plain coalesced stores
    unsigned int* dst = hist + (size_t)blockIdx.x * HTOT;
    for (int i = t; i < HTOT; i += TPB) {
        int j = i << 2;
        dst[i] = sh[j] + sh[j + 1] + sh[j + 2] + sh[j + 3];
    }
}

// Tree-merge NB private copies into MPARTS copies. grid = (ceil(HTOT/256), MPARTS)
__global__ __launch_bounds__(256) void lovasz_merge(
    const unsigned int* __restrict__ hist,
    unsigned int* __restrict__ merged)
{
    int bin  = blockIdx.x * 256 + threadIdx.x;
    if (bin >= HTOT) return;
    int part = blockIdx.y;
    int lo = part * NB / MPARTS, hi = (part + 1) * NB / MPARTS;
    unsigned int s = 0;
    for (int k = lo; k < hi; ++k) s += hist[(size_t)k * HTOT + bin];
    merged[(size_t)part * HTOT + bin] = s;
}

// One block per class; 1 bin/thread; telescoped Lovasz over descending bins.
__global__ __launch_bounds__(NBINS) void lovasz_reduce(
    const unsigned int* __restrict__ merged,
    float* __restrict__ out)
{
    const int c = blockIdx.x;
    const int t = threadIdx.x;

    __shared__ unsigned int s_cnt[NBINS], s_m[NBINS];
    __shared__ double s_loss[NBINS];

    const unsigned int* h0 = merged + (size_t)(c * 2 + 0) * NBINS;
    const unsigned int* h1 = merged + (size_t)(c * 2 + 1) * NBINS;

    const int bin = NBINS - 1 - t;     // thread t owns the t-th highest-err bin
    unsigned int a = 0, b = 0;
    for (int k = 0; k < MPARTS; ++k) {
        a += h0[(size_t)k * HTOT + bin];
        b += h1[(size_t)k * HTOT + bin];
    }
    s_cnt[t] = a + b; s_m[t] = b;
    __syncthreads();

    // exclusive scan over threads (descending-err order) + total fg count
    unsigned long long nb = 0, mb = 0, gts = 0;
    for (int i = 0; i < NBINS; ++i) {
        unsigned int ci = s_cnt[i], mi = s_m[i];
        if (i < t) { nb += ci; mb += mi; }
        gts += mi;
    }
    double gtsd = (double)gts;

    // telescoped contribution of this bin (fp64: jacc differences cancel)
    double loss = 0.0;
    unsigned int cc = a + b;
    if (cc) {
        double jb = (nb == 0) ? 0.0
            : 1.0 - (gtsd - (double)mb) / (gtsd + (double)nb - (double)mb);
        unsigned long long n2 = nb + cc, m2 = mb + b;
        double ja = 1.0 - (gtsd - (double)m2) / (gtsd + (double)n2 - (double)m2);
        loss = (((double)bin + 0.5) / (double)NBINS) * (ja - jb);
    }
    s_loss[t] = loss;
    __syncthreads();
    for (int s = NBINS / 2; s > 0; s >>= 1) {
        if (t < s) s_loss[t] += s_loss[t + s];
        __syncthreads();
    }
    if (t == 0) atomicAdd(out, (float)(s_loss[0] / (double)NCLS));
}

extern "C" void kernel_launch(void* const* d_in, const int* in_sizes, int n_in,
                              void* d_out, int out_size, void* d_ws, size_t ws_size,
                              hipStream_t stream)
{
    const float* logits = (const float*)d_in[0];
    const int*   labels = (const int*)d_in[1];
    float* out = (float*)d_out;
    unsigned int* hist = (unsigned int*)d_ws;

    hipMemsetAsync(d_out, 0, sizeof(float) * (size_t)out_size, stream);

    const size_t need = (size_t)(NB + MPARTS) * HTOT * 4;  // ~10.1 MB
    if (ws_size < need) return;  // ws too small — leave out=0 rather than fault

    unsigned int* merged = hist + (size_t)NB * HTOT;

    lovasz_hist<<<NB, TPB, 0, stream>>>(logits, labels, hist);
    dim3 mg((HTOT + 255) / 256, MPARTS);
    lovasz_merge<<<mg, 256, 0, stream>>>(hist, merged);
    lovasz_reduce<<<NCLS, NBINS, 0, stream>>>(merged, out);
}